// Round 1
// 415.638 us; speedup vs baseline: 1.0433x; 1.0433x over previous
//
#include <hip/hip_runtime.h>

#define DIM 128

typedef float v4f __attribute__((ext_vector_type(4)));

// Half-wave (32 lanes) per row of 128 floats; each lane owns a float4 column
// slice. ILP=2: each half-wave processes TWO rows per iteration so the two
// shuffle-reduce chains interleave and 2x the memory stays in flight while
// the ds_swizzle butterfly latency is being paid.
__global__ __launch_bounds__(256) void qop_kernel(
    const float* __restrict__ sr, const float* __restrict__ si,
    const float* __restrict__ p,
    float* __restrict__ out_r, float* __restrict__ out_i, int M)
{
    const int lane32 = threadIdx.x & 31;   // float4 index within the row
    const int half   = threadIdx.x >> 5;   // 0..7 half-wave id in block
    const int halves = blockDim.x >> 5;    // 8

    // Per-lane column parameters (constant across all rows this lane touches).
    const v4f p4 = reinterpret_cast<const v4f*>(p)[lane32];
    v4f d4;
    d4.x = 1.0f / (1.0f + __expf(-p4.x)) - p4.x * p4.x;
    d4.y = 1.0f / (1.0f + __expf(-p4.y)) - p4.y * p4.y;
    d4.z = 1.0f / (1.0f + __expf(-p4.z)) - p4.z * p4.z;
    d4.w = 1.0f / (1.0f + __expf(-p4.w)) - p4.w * p4.w;

    const v4f* sr4 = reinterpret_cast<const v4f*>(sr);
    const v4f* si4 = reinterpret_cast<const v4f*>(si);
    v4f* or4 = reinterpret_cast<v4f*>(out_r);
    v4f* oi4 = reinterpret_cast<v4f*>(out_i);

    const long long rowsPerIter = (long long)halves * 2;   // 16 rows/block/iter

    for (long long base = (long long)blockIdx.x * rowsPerIter;
         base < M;
         base += (long long)gridDim.x * rowsPerIter)
    {
        const long long row0 = base + half;
        const long long row1 = base + halves + half;
        const bool ok0 = row0 < M;
        const bool ok1 = row1 < M;
        const long long idx0 = row0 * 32 + lane32;
        const long long idx1 = row1 * 32 + lane32;

        v4f r0 = {0.f, 0.f, 0.f, 0.f}, i0 = {0.f, 0.f, 0.f, 0.f};
        v4f r1 = {0.f, 0.f, 0.f, 0.f}, i1 = {0.f, 0.f, 0.f, 0.f};
        // Streaming data, zero reuse (1 GB >> 32 MB L2): nontemporal.
        if (ok0) {
            r0 = __builtin_nontemporal_load(sr4 + idx0);
            i0 = __builtin_nontemporal_load(si4 + idx0);
        }
        if (ok1) {
            r1 = __builtin_nontemporal_load(sr4 + idx1);
            i1 = __builtin_nontemporal_load(si4 + idx1);
        }

        // Per-lane partials for both rows: dot-with-p and plain sum, real+imag.
        float ar0 = r0.x * p4.x + r0.y * p4.y + r0.z * p4.z + r0.w * p4.w;
        float sr0 = r0.x + r0.y + r0.z + r0.w;
        float ai0 = i0.x * p4.x + i0.y * p4.y + i0.z * p4.z + i0.w * p4.w;
        float si0 = i0.x + i0.y + i0.z + i0.w;

        float ar1 = r1.x * p4.x + r1.y * p4.y + r1.z * p4.z + r1.w * p4.w;
        float sr1 = r1.x + r1.y + r1.z + r1.w;
        float ai1 = i1.x * p4.x + i1.y * p4.y + i1.z * p4.z + i1.w * p4.w;
        float si1 = i1.x + i1.y + i1.z + i1.w;

        // Butterfly reduce across the 32 lanes of each half-wave. XOR masks
        // < 32 never cross the half-wave boundary in a wave64. 8 independent
        // chains per step pipeline the ds_swizzle latency.
        #pragma unroll
        for (int m = 16; m >= 1; m >>= 1) {
            ar0 += __shfl_xor(ar0, m, 64);
            ai0 += __shfl_xor(ai0, m, 64);
            sr0 += __shfl_xor(sr0, m, 64);
            si0 += __shfl_xor(si0, m, 64);
            ar1 += __shfl_xor(ar1, m, 64);
            ai1 += __shfl_xor(ai1, m, 64);
            sr1 += __shfl_xor(sr1, m, 64);
            si1 += __shfl_xor(si1, m, 64);
        }

        const float cr0 = ar0 + si0;   // coefficient of p_j in out_real
        const float ci0 = ai0 - sr0;   // coefficient of p_j in out_imag
        const float cr1 = ar1 + si1;
        const float ci1 = ai1 - sr1;

        if (ok0) {
            v4f o_r = cr0 * p4 + r0 * d4 - ai0;
            v4f o_i = ar0 + ci0 * p4 + i0 * d4;
            __builtin_nontemporal_store(o_r, or4 + idx0);
            __builtin_nontemporal_store(o_i, oi4 + idx0);
        }
        if (ok1) {
            v4f o_r = cr1 * p4 + r1 * d4 - ai1;
            v4f o_i = ar1 + ci1 * p4 + i1 * d4;
            __builtin_nontemporal_store(o_r, or4 + idx1);
            __builtin_nontemporal_store(o_i, oi4 + idx1);
        }
    }
}

extern "C" void kernel_launch(void* const* d_in, const int* in_sizes, int n_in,
                              void* d_out, int out_size, void* d_ws, size_t ws_size,
                              hipStream_t stream) {
    const float* sr = (const float*)d_in[0];
    const float* si = (const float*)d_in[1];
    const float* p  = (const float*)d_in[2];
    float* out = (float*)d_out;

    const int M = in_sizes[0] / DIM;          // 16*16384 = 262144 rows
    float* out_r = out;
    float* out_i = out + (size_t)M * DIM;

    const int block = 256;
    const int rowsPerBlock = (block / 32) * 2;             // 16 rows/block
    int blocks = (M + rowsPerBlock - 1) / rowsPerBlock;    // 16384

    qop_kernel<<<blocks, block, 0, stream>>>(sr, si, p, out_r, out_i, M);
}